// Round 1
// baseline (664.785 us; speedup 1.0000x reference)
//
#include <hip/hip_runtime.h>

// GaussianSoftmax: out[b,n,m] = softmax_m( exp( -max(||x_n-x_m||^2, 0) / sigma ) )
// X: [8, 4096, 16] fp32, sigma: [1] fp32, out: [8, 4096, 4096] fp32 (512 MiB).
// HBM-write-bound design: one block computes TN=4 full output rows; e=exp(g)
// staged in LDS (64 KB -> 2 blocks/CU); output written exactly once, coalesced.

constexpr int Bn  = 8;
constexpr int N   = 4096;
constexpr int F   = 16;
constexpr int TN  = 4;    // output rows per block
constexpr int BLK = 256;  // threads per block

__global__ __launch_bounds__(BLK, 2)
void gaussian_softmax_kernel(const float* __restrict__ X,
                             const float* __restrict__ sigma_p,
                             float* __restrict__ out) {
    __shared__ float lds_e[TN][N];          // 64 KiB: exp(gaussian) rows
    __shared__ float xn_sh[TN * F];         // the 4 query rows
    __shared__ float red[TN][BLK / 64];     // cross-wave reduction

    const int tid = threadIdx.x;
    const int b   = blockIdx.y;
    const int n0  = blockIdx.x * TN;
    const float* Xb = X + (size_t)b * N * F;

    // stage the TN query rows through LDS (broadcast to all threads)
    if (tid < TN * F) xn_sh[tid] = Xb[(size_t)n0 * F + tid];
    __syncthreads();

    float xn[TN][F];
    #pragma unroll
    for (int r = 0; r < TN; ++r)
        #pragma unroll
        for (int f = 0; f < F; ++f)
            xn[r][f] = xn_sh[r * F + f];

    float sqn[TN];
    #pragma unroll
    for (int r = 0; r < TN; ++r) {
        float s = 0.f;
        #pragma unroll
        for (int f = 0; f < F; ++f) s = fmaf(xn[r][f], xn[r][f], s);
        sqn[r] = s;
    }

    const float inv_sigma = 1.0f / sigma_p[0];

    float sum[TN];
    #pragma unroll
    for (int r = 0; r < TN; ++r) sum[r] = 0.f;

    // main loop: each thread handles 16 m-columns, reused across TN rows
    for (int it = 0; it < N / BLK; ++it) {
        const int m = it * BLK + tid;
        const float4* xmp = (const float4*)(Xb + (size_t)m * F);  // 64B-aligned
        float4 v0 = xmp[0], v1 = xmp[1], v2 = xmp[2], v3 = xmp[3];
        float xm[F] = {v0.x, v0.y, v0.z, v0.w, v1.x, v1.y, v1.z, v1.w,
                       v2.x, v2.y, v2.z, v2.w, v3.x, v3.y, v3.z, v3.w};

        float sqm = 0.f;
        #pragma unroll
        for (int f = 0; f < F; ++f) sqm = fmaf(xm[f], xm[f], sqm);

        #pragma unroll
        for (int r = 0; r < TN; ++r) {
            float d = 0.f;
            #pragma unroll
            for (int f = 0; f < F; ++f) d = fmaf(xn[r][f], xm[f], d);
            float sqd = sqn[r] + sqm - 2.0f * d;
            sqd = fmaxf(sqd, 0.0f);
            float g = __expf(-sqd * inv_sigma);
            float e = __expf(g);
            lds_e[r][m] = e;
            sum[r] += e;
        }
    }

    // softmax denominator: wave shuffle reduce, then cross-wave via LDS
    #pragma unroll
    for (int r = 0; r < TN; ++r) {
        float s = sum[r];
        #pragma unroll
        for (int off = 32; off > 0; off >>= 1) s += __shfl_down(s, off, 64);
        if ((tid & 63) == 0) red[r][tid >> 6] = s;
    }
    __syncthreads();   // also guarantees all lds_e writes are visible

    float inv[TN];
    #pragma unroll
    for (int r = 0; r < TN; ++r) {
        float t = red[r][0] + red[r][1] + red[r][2] + red[r][3];
        inv[r] = 1.0f / t;
    }

    // epilogue: normalized, coalesced float4 stores; output written exactly once
    float* outb = out + ((size_t)b * N + (size_t)n0) * (size_t)N;
    #pragma unroll
    for (int r = 0; r < TN; ++r) {
        #pragma unroll
        for (int j = 0; j < N / (BLK * 4); ++j) {
            const int c = j * (BLK * 4) + tid * 4;
            float4 v = *(const float4*)&lds_e[r][c];
            v.x *= inv[r]; v.y *= inv[r]; v.z *= inv[r]; v.w *= inv[r];
            *(float4*)&outb[(size_t)r * N + c] = v;
        }
    }
}

extern "C" void kernel_launch(void* const* d_in, const int* in_sizes, int n_in,
                              void* d_out, int out_size, void* d_ws, size_t ws_size,
                              hipStream_t stream) {
    const float* X     = (const float*)d_in[0];
    const float* sigma = (const float*)d_in[1];
    float* out         = (float*)d_out;

    dim3 grid(N / TN, Bn);
    dim3 block(BLK);
    gaussian_softmax_kernel<<<grid, block, 0, stream>>>(X, sigma, out);
}

// Round 2
// 617.922 us; speedup vs baseline: 1.0758x; 1.0758x over previous
//
#include <hip/hip_runtime.h>

// GaussianSoftmax: out[b,n,m] = softmax_m( exp( exp( -max(||x_n-x_m||^2,0) / sigma ) ) normalization )
// X: [8, 4096, 16] fp32, sigma: [1], out: [8, 4096, 4096] fp32 (512 MiB).
// R1: BLK 256->512 (same 64 KiB LDS, 2 blocks/CU -> 4 waves/SIMD for latency
// hiding); query rows via uniform scalar loads (SGPRs, not VGPRs); dot on
// explicit float4 components (no spillable arrays). Output written exactly once.

constexpr int Bn  = 8;
constexpr int N   = 4096;
constexpr int F   = 16;
constexpr int TN  = 4;     // output rows per block
constexpr int BLK = 512;   // 8 waves/block; 2 blocks/CU (LDS-bound) = 4 waves/SIMD
constexpr int WPB = BLK / 64;

__device__ __forceinline__ float dot4(float4 a, float4 b) {
    return fmaf(a.x, b.x, fmaf(a.y, b.y, fmaf(a.z, b.z, a.w * b.w)));
}

__global__ __launch_bounds__(BLK, 4)
void gaussian_softmax_kernel(const float* __restrict__ X,
                             const float* __restrict__ sigma_p,
                             float* __restrict__ out) {
    __shared__ float lds_e[TN][N];        // 64 KiB: exp(gaussian) rows
    __shared__ float red[TN][WPB];        // cross-wave reduction

    const int tid = threadIdx.x;
    const int b   = blockIdx.y;
    const int n0  = blockIdx.x * TN;
    const float* Xb = X + (size_t)b * N * F;

    // Query rows: thread-uniform addresses -> compiler emits scalar (SGPR) loads.
    float4 q0[TN], q1[TN], q2[TN], q3[TN];
    float  sqn[TN];
    #pragma unroll
    for (int r = 0; r < TN; ++r) {
        const float4* qp = (const float4*)(Xb + (size_t)(n0 + r) * F);
        q0[r] = qp[0]; q1[r] = qp[1]; q2[r] = qp[2]; q3[r] = qp[3];
        sqn[r] = dot4(q0[r], q0[r]) + dot4(q1[r], q1[r])
               + dot4(q2[r], q2[r]) + dot4(q3[r], q3[r]);
    }

    const float neg_inv_sigma = -1.0f / sigma_p[0];

    float sum[TN];
    #pragma unroll
    for (int r = 0; r < TN; ++r) sum[r] = 0.f;

    // Main loop: 8 iterations, each thread one m-column per iter.
    #pragma unroll 2
    for (int it = 0; it < N / BLK; ++it) {
        const int m = it * BLK + tid;
        const float4* xmp = (const float4*)(Xb + (size_t)m * F);  // 64B-aligned
        const float4 a0 = xmp[0], a1 = xmp[1], a2 = xmp[2], a3 = xmp[3];

        const float sqm = dot4(a0, a0) + dot4(a1, a1) + dot4(a2, a2) + dot4(a3, a3);

        #pragma unroll
        for (int r = 0; r < TN; ++r) {
            float d = dot4(q0[r], a0) + dot4(q1[r], a1)
                    + dot4(q2[r], a2) + dot4(q3[r], a3);
            float sqd = fmaf(-2.0f, d, sqn[r] + sqm);
            sqd = fmaxf(sqd, 0.0f);
            float g = __expf(sqd * neg_inv_sigma);
            float e = __expf(g);
            lds_e[r][m] = e;
            sum[r] += e;
        }
    }

    // Softmax denominator: wave shuffle reduce, then cross-wave via LDS.
    #pragma unroll
    for (int r = 0; r < TN; ++r) {
        float s = sum[r];
        #pragma unroll
        for (int off = 32; off > 0; off >>= 1) s += __shfl_down(s, off, 64);
        if ((tid & 63) == 0) red[r][tid >> 6] = s;
    }
    __syncthreads();   // lds_e + red all visible

    float inv[TN];
    #pragma unroll
    for (int r = 0; r < TN; ++r) {
        float t = 0.f;
        #pragma unroll
        for (int w = 0; w < WPB; ++w) t += red[r][w];
        inv[r] = 1.0f / t;
    }

    // Epilogue: normalized, coalesced float4 stores; output written exactly once.
    float* outb = out + ((size_t)b * N + (size_t)n0) * (size_t)N;
    #pragma unroll
    for (int r = 0; r < TN; ++r) {
        #pragma unroll
        for (int j = 0; j < N / (BLK * 4); ++j) {
            const int c = j * (BLK * 4) + tid * 4;
            float4 v = *(const float4*)&lds_e[r][c];
            v.x *= inv[r]; v.y *= inv[r]; v.z *= inv[r]; v.w *= inv[r];
            *(float4*)&outb[(size_t)r * N + c] = v;
        }
    }
}

extern "C" void kernel_launch(void* const* d_in, const int* in_sizes, int n_in,
                              void* d_out, int out_size, void* d_ws, size_t ws_size,
                              hipStream_t stream) {
    const float* X     = (const float*)d_in[0];
    const float* sigma = (const float*)d_in[1];
    float* out         = (float*)d_out;

    dim3 grid(N / TN, Bn);
    dim3 block(BLK);
    gaussian_softmax_kernel<<<grid, block, 0, stream>>>(X, sigma, out);
}